// Round 5
// baseline (11722.779 us; speedup 1.0000x reference)
//
#include <hip/hip_runtime.h>

#define KP 32   // particles
#define BN 256  // batch
#define TN 32   // time steps
#define ROWS (KP*BN) // 8192
#define NBLK 256
#define NTHR 512

// ---------------- barrier state init (ws is poisoned 0xAA each call) ----------------
__global__ void k_bar_init(unsigned* __restrict__ bar) {
    if (threadIdx.x < 2) bar[threadIdx.x] = 0u;
}

// ---------------- device-scope grid barrier (generation counting) ----------------
__device__ __forceinline__ void gbar(unsigned* __restrict__ ctr, unsigned* __restrict__ gen) {
    __threadfence();          // publish this block's global writes (agent scope)
    __syncthreads();
    if (threadIdx.x == 0) {
        unsigned g = __hip_atomic_load(gen, __ATOMIC_RELAXED, __HIP_MEMORY_SCOPE_AGENT);
        unsigned a = __hip_atomic_fetch_add(ctr, 1u, __ATOMIC_ACQ_REL, __HIP_MEMORY_SCOPE_AGENT);
        if (a == NBLK - 1u) {
            __hip_atomic_store(ctr, 0u, __ATOMIC_RELAXED, __HIP_MEMORY_SCOPE_AGENT);
            __hip_atomic_store(gen, g + 1u, __ATOMIC_RELEASE, __HIP_MEMORY_SCOPE_AGENT);
        } else {
            while (__hip_atomic_load(gen, __ATOMIC_ACQUIRE, __HIP_MEMORY_SCOPE_AGENT) == g)
                __builtin_amdgcn_s_sleep(1);
        }
    }
    __syncthreads();
    __threadfence();          // invalidate L1 so remote blocks' writes are seen
}

union SharedU {
    struct { float hT[32 * 128]; int hsl[32], csl[32]; float pp[32][2], qq[32][2]; } ls;
    struct { float hb[128], cb[128], hcp[128], aa[32], beta[32], red[128];
             int hsl[32], csl[32]; float yts; } at;
    struct { float pr[32][33]; int ord[32][32]; float es[32][33]; float Sv[32];
             float lw[32][33]; } rs;
    struct { float row[4][128]; } ep;
};

__global__ __launch_bounds__(NTHR, 2)
void k_persist(const float* __restrict__ enc, const float* __restrict__ yprev,
               const float* __restrict__ eps, const float* __restrict__ gum,
               const float* __restrict__ W1, const float* __restrict__ b1,
               const float* __restrict__ W2, const float* __restrict__ b2v,
               const float* __restrict__ Wih, const float* __restrict__ Whh,
               const float* __restrict__ bih, const float* __restrict__ bhh,
               const float* __restrict__ fcW, const float* __restrict__ fcb,
               const float* __restrict__ fdW, const float* __restrict__ fdb,
               const float* __restrict__ feW, const float* __restrict__ feb,
               const float* __restrict__ varW, const float* __restrict__ varb,
               const float* __restrict__ pdW, const float* __restrict__ pdb,
               float* __restrict__ encp, float* __restrict__ h2A, float* __restrict__ c2A,
               float* __restrict__ h2B, float* __restrict__ c2B,
               float* __restrict__ ctxg, float* __restrict__ ytg, float* __restrict__ vspg,
               float* __restrict__ proj, float* __restrict__ qv,
               int* __restrict__ hsrc, int* __restrict__ csrc,
               float* __restrict__ Wre, float* __restrict__ wihre, float* __restrict__ bre,
               unsigned* __restrict__ bar, float* __restrict__ out) {
    __shared__ SharedU sh;
    const int tid = threadIdx.x;
    const int bid = blockIdx.x;
    unsigned* ctr = bar;
    unsigned* gen = bar + 1;

    // ======== pre-phase: zero state, identity indices, encp, Wre ========
    {
        float4* z = (float4*)h2A + bid * 2048;      // h2A,c2A contiguous: 2M floats
#pragma unroll
        for (int i = 0; i < 4; ++i)
            z[tid + NTHR * i] = make_float4(0.f, 0.f, 0.f, 0.f);
        if (tid < 32) {
            int row = bid * 32 + tid;
            hsrc[row] = row >> 8;
            csrc[row] = row >> 8;
        }
        if (tid < 64) {
            int i = bid * 64 + tid;                 // 16384 total
            int dd = i >> 7, d0 = i & 127;
            float4 v;
            v.x = Whh[dd * 512 + 0 * 128 + d0];
            v.y = Whh[dd * 512 + 1 * 128 + d0];
            v.z = Whh[dd * 512 + 2 * 128 + d0];
            v.w = Whh[dd * 512 + 3 * 128 + d0];
            ((float4*)Wre)[i] = v;
            if (i < 128) {
                float4 a;
                a.x = Wih[0 * 128 + d0]; a.y = Wih[1 * 128 + d0];
                a.z = Wih[2 * 128 + d0]; a.w = Wih[3 * 128 + d0];
                ((float4*)wihre)[d0] = a;
                float4 bb;
                bb.x = bih[0 * 128 + d0] + bhh[0 * 128 + d0];
                bb.y = bih[1 * 128 + d0] + bhh[1 * 128 + d0];
                bb.z = bih[2 * 128 + d0] + bhh[2 * 128 + d0];
                bb.w = bih[3 * 128 + d0] + bhh[3 * 128 + d0];
                ((float4*)bre)[d0] = bb;
            }
        }
        // encp: 32 bt per block, 4 at a time
        int sub = tid >> 7, e = tid & 127;
        for (int g8 = 0; g8 < 8; ++g8) {
            int bt = bid * 32 + g8 * 4 + sub;
            sh.ep.row[sub][e] = enc[bt * 128 + e];
            __syncthreads();
            float acc = 0.f;
#pragma unroll 8
            for (int c = 0; c < 128; ++c)
                acc = fmaf(sh.ep.row[sub][c], W1[(256 + c) * 128 + e], acc);
            encp[bt * 128 + e] = acc;
            __syncthreads();
        }
    }
    gbar(ctr, gen);

    float* hc = h2A; float* cc = c2A; float* hn = h2B; float* cn = c2B;

    for (int t = 0; t < TN; ++t) {
        // ======== attn phase: block = batch b (orig 256-thr code, tid<256 gated) ========
        {
            auto& A = sh.at;
            const int b = bid;
            if (tid < 32) A.hsl[tid] = hsrc[tid * BN + b];
            else if (tid < 64) A.csl[tid - 32] = csrc[(tid - 32) * BN + b];
            __syncthreads();

            if (tid < 128) {
                float s = 0.f;
#pragma unroll 4
                for (int k = 0; k < KP; ++k)
                    s += hc[((size_t)A.hsl[k] * BN + b) * 128 + tid];
                A.hb[tid] = s * (1.f / 32.f);
            } else if (tid < 256) {
                int d = tid - 128;
                float s = 0.f;
#pragma unroll 4
                for (int k = 0; k < KP; ++k)
                    s += cc[((size_t)A.csl[k] * BN + b) * 128 + d];
                A.cb[d] = s * (1.f / 32.f);
            }
            __syncthreads();

            // phase 2
            float acc2 = 0.f;
            {
                int e = tid & 127, half = (tid >> 7) & 1;
                if (tid < 256) {
                    const float* Wb  = W1 + half * 128 * 128;
                    const float* hcl = half ? A.cb : A.hb;
#pragma unroll 8
                    for (int d = 0; d < 128; ++d)
                        acc2 = fmaf(hcl[d], Wb[d * 128 + e], acc2);
                    if (half) A.red[e] = acc2;
                }
            }
            __syncthreads();
            if (tid < 128) A.hcp[tid] = acc2 + A.red[tid] + b1[tid];
            __syncthreads();

            // phase 3
            if (tid < 256) {
                int w = tid >> 6, lane = tid & 63;
                for (int tt = 0; tt < 8; ++tt) {
                    int tq = w * 8 + tt;
                    float v = 0.f;
#pragma unroll
                    for (int hh = 0; hh < 2; ++hh) {
                        int e = lane + 64 * hh;
                        v += tanhf(A.hcp[e] + encp[(b * TN + tq) * 128 + e]) * W2[e];
                    }
#pragma unroll
                    for (int off = 32; off; off >>= 1) v += __shfl_xor(v, off, 64);
                    if (lane == 0) A.aa[tq] = v + b2v[0];
                }
            }
            __syncthreads();

            // phase 4: softmax
            if (tid < 32) {
                float m = -1e30f;
                for (int i = 0; i < 32; ++i) m = fmaxf(m, A.aa[i]);
                float s = 0.f;
                for (int i = 0; i < 32; ++i) s += expf(A.aa[i] - m);
                A.beta[tid] = expf(A.aa[tid] - m) / s;
            }
            __syncthreads();

            // context + y_tilde
            if (tid < 128) {
                float acc = 0.f;
#pragma unroll 4
                for (int tq = 0; tq < 32; ++tq)
                    acc = fmaf(A.beta[tq], enc[(b * TN + tq) * 128 + tid], acc);
                ctxg[b * 128 + tid] = acc;
                A.red[tid] = acc * fcW[tid];
            }
            __syncthreads();
            if (tid < 64) A.red[tid] += A.red[tid + 64];
            __syncthreads();
            if (tid < 64) {
                float v = A.red[tid];
#pragma unroll
                for (int off = 32; off; off >>= 1) v += __shfl_xor(v, off, 64);
                if (tid == 0) {
                    float yv = v + yprev[b * TN + t] * fcW[128] + fcb[0];
                    A.yts = yv;
                    ytg[b] = yv;
                }
            }
            __syncthreads();

            // phase 6: var + softplus
            if (tid < 128) {
                int j = tid;
                float v = fmaf(A.yts, varW[j], varb[j]);
#pragma unroll 8
                for (int d = 0; d < 128; ++d)
                    v = fmaf(A.hb[d], varW[(1 + d) * 128 + j], v);
                vspg[b * 128 + j] = fmaxf(v, 0.f) + log1pf(expf(-fabsf(v)));
            }
        }
        gbar(ctr, gen);

        // ======== lstm phase: block owns rows [bid*32, bid*32+32) ========
        {
            auto& L = sh.ls;
            int row0 = bid * 32;
            int b0   = row0 & 255;
            int w = tid >> 6, c0 = tid & 63;
            int wr = w & 3, dh = w >> 2;
            int d0 = dh * 64 + c0;

            if (tid < 32) L.hsl[tid] = hsrc[row0 + tid];
            else if (tid < 64) L.csl[tid - 32] = csrc[row0 + tid - 32];
            __syncthreads();

#pragma unroll
            for (int i = 0; i < 2; ++i) {
                int f4 = tid + NTHR * i;
                int lr = f4 >> 5, off = f4 & 31;
                ((float4*)L.hT)[f4] =
                    ((const float4*)hc)[((size_t)L.hsl[lr] * BN + b0 + lr) * 32 + off];
            }
            __syncthreads();

            float4 wih4 = ((const float4*)wihre)[d0];
            float4 b4   = ((const float4*)bre)[d0];
            const float* wihp = (const float*)&wih4;
            const float* bp   = (const float*)&b4;
            float acc[8][4];
#pragma unroll
            for (int r = 0; r < 8; ++r) {
                float ytv = ytg[b0 + wr * 8 + r];
#pragma unroll
                for (int g = 0; g < 4; ++g)
                    acc[r][g] = fmaf(ytv, wihp[g], bp[g]);
            }

            const float4* wp   = (const float4*)Wre + d0;
            const float*  hrow = L.hT + (wr * 8) * 128;
#pragma unroll 2
            for (int dq = 0; dq < 32; ++dq) {
                float4 wv[4];
#pragma unroll
                for (int j = 0; j < 4; ++j) wv[j] = wp[(dq * 4 + j) * 128];
                float4 hv[8];
#pragma unroll
                for (int r = 0; r < 8; ++r)
                    hv[r] = *(const float4*)&hrow[r * 128 + dq * 4];
#pragma unroll
                for (int j = 0; j < 4; ++j) {
#pragma unroll
                    for (int r = 0; r < 8; ++r) {
                        float hvj = ((const float*)&hv[r])[j];
#pragma unroll
                        for (int g = 0; g < 4; ++g)
                            acc[r][g] = fmaf(hvj, ((const float*)&wv[j])[g], acc[r][g]);
                    }
                }
            }

            float fdv = fdW[d0], pdv = pdW[d0];
#pragma unroll
            for (int r = 0; r < 8; ++r) {
                int lr  = wr * 8 + r;
                int row = row0 + lr;
                int bb  = b0 + lr;
                float gi = acc[r][0], gf = acc[r][1], gg = acc[r][2], go = acc[r][3];
                float si = 1.f / (1.f + expf(-gi));
                float sf = 1.f / (1.f + expf(-gf));
                float so = 1.f / (1.f + expf(-go));
                float tg = tanhf(gg);
                float cold = cc[((size_t)L.csl[lr] * BN + bb) * 128 + d0];
                float cnv = sf * cold + si * tg;
                float hnv = so * tanhf(cnv);
                hnv = fmaf(eps[((size_t)t * ROWS + row) * 128 + d0], vspg[bb * 128 + d0], hnv);
                cn[(size_t)row * 128 + d0] = cnv;
                hn[(size_t)row * 128 + d0] = hnv;
                float p = hnv * fdv, q = hnv * pdv;
#pragma unroll
                for (int off = 32; off; off >>= 1) {
                    p += __shfl_xor(p, off, 64);
                    q += __shfl_xor(q, off, 64);
                }
                if (c0 == 0) { L.pp[lr][dh] = p; L.qq[lr][dh] = q; }
            }
            __syncthreads();
            if (tid < 32) proj[row0 + tid] = L.pp[tid][0] + L.pp[tid][1];
            else if (tid < 64) qv[row0 + tid - 32] = L.qq[tid - 32][0] + L.qq[tid - 32][1];
        }
        gbar(ctr, gen);

        // ======== resample phase: blocks 0..7, chunk m = bid; 512 thr = 16 bl x 32 j, 2 passes ========
        if (bid < 8) {
            auto& R = sh.rs;
            int sub = tid >> 5;          // 0..15
            int j   = tid & 31;
            int m   = bid;

#pragma unroll
            for (int p = 0; p < 2; ++p) {
                int bl = sub + p * 16, b = m * 32 + bl;
                R.pr[bl][j] = proj[j * BN + b];
            }
            __syncthreads();
#pragma unroll
            for (int p = 0; p < 2; ++p) {
                int bl = sub + p * 16;
                float pj = R.pr[bl][j];
                int r = 0;
#pragma unroll 8
                for (int l = 0; l < 32; ++l) {
                    float pl = R.pr[bl][l];
                    r += (pl < pj) || (pl == pj && l < j);
                }
                R.ord[bl][r] = j;
            }
            __syncthreads();
#pragma unroll
            for (int p = 0; p < 2; ++p) {
                int bl = sub + p * 16, b = m * 32 + bl;
                int jo = R.ord[bl][j];
                float lp = qv[jo * BN + b] + ytg[b] * pdW[128] + pdb[0];
                R.es[j][bl] = expf(lp);
            }
            __syncthreads();
            if (tid < 32) {
                float s = 0.f;
#pragma unroll 8
                for (int l = 0; l < 32; ++l) s += R.es[tid][l];
                R.Sv[tid] = s;
            }
            __syncthreads();
#pragma unroll
            for (int p = 0; p < 2; ++p) {
                int bl = sub + p * 16;
                R.lw[bl][j] = logf(R.es[j][bl] / R.Sv[j] + 1e-30f);
            }
            __syncthreads();
#pragma unroll
            for (int p = 0; p < 2; ++p) {
                int bl = sub + p * 16, b = m * 32 + bl;
                const float* gb = gum + (((size_t)t * BN + b) * KP + j) * KP;
                float best = -1e38f;
                int bi = 0;
#pragma unroll 8
                for (int l = 0; l < 32; ++l) {
                    float v = R.lw[bl][l] + gb[l];
                    if (v > best) { best = v; bi = l; }
                }
                hsrc[j * BN + b] = R.ord[bl][bi];
                csrc[j * BN + b] = bi;
            }
        }
        gbar(ctr, gen);

        float* th = hc; hc = hn; hn = th;
        float* tc = cc; cc = cn; cn = tc;
    }

    // ======== final: block b computes out[b] (orig k_final per-b arithmetic) ========
    if (tid < 64) {
        int b = bid, lane = tid;
        float acc = 0.f;
#pragma unroll
        for (int hh = 0; hh < 2; ++hh) {
            int d = lane + 64 * hh;
            float s = 0.f;
#pragma unroll 4
            for (int k = 0; k < KP; ++k) {
                int hs = hsrc[k * BN + b];
                s += hc[((size_t)hs * BN + b) * 128 + d];
            }
            acc = fmaf(s * (1.f / 32.f), fdW[d], acc);
            acc = fmaf(ctxg[b * 128 + d], feW[d], acc);
        }
#pragma unroll
        for (int off = 32; off; off >>= 1) acc += __shfl_xor(acc, off, 64);
        if (lane == 0) out[b] = acc + fdb[0] + feb[0];
    }
}

extern "C" void kernel_launch(void* const* d_in, const int* in_sizes, int n_in,
                              void* d_out, int out_size, void* d_ws, size_t ws_size,
                              hipStream_t stream) {
    const float* enc   = (const float*)d_in[0];
    const float* yprev = (const float*)d_in[1];
    const float* eps   = (const float*)d_in[2];
    const float* gum   = (const float*)d_in[3];
    const float* aW1   = (const float*)d_in[4];
    const float* ab1   = (const float*)d_in[5];
    const float* aW2   = (const float*)d_in[6];
    const float* ab2   = (const float*)d_in[7];
    const float* Wih   = (const float*)d_in[8];
    const float* Whh   = (const float*)d_in[9];
    const float* bih   = (const float*)d_in[10];
    const float* bhh   = (const float*)d_in[11];
    const float* fcW   = (const float*)d_in[12];
    const float* fcb   = (const float*)d_in[13];
    const float* fdW   = (const float*)d_in[14];
    const float* fdb   = (const float*)d_in[15];
    const float* feW   = (const float*)d_in[16];
    const float* feb   = (const float*)d_in[17];
    const float* varW  = (const float*)d_in[18];
    const float* varb  = (const float*)d_in[19];
    const float* pdW   = (const float*)d_in[20];
    const float* pdb   = (const float*)d_in[21];
    float* out = (float*)d_out;

    float* ws    = (float*)d_ws;
    float* encp  = ws;                        // 1,048,576
    float* h2A   = ws + 1048576;              // h2A,c2A contiguous for zero-init
    float* c2A   = ws + 2097152;
    float* h2B   = ws + 3145728;
    float* c2B   = ws + 4194304;
    float* ctx   = ws + 5242880;              // 32,768
    float* ytg   = ws + 5275648;              // 256
    float* vsp   = ws + 5275904;              // 32,768
    float* proj  = ws + 5308672;              // 8,192
    float* qv    = ws + 5316864;              // 8,192
    int*   hsrc  = (int*)(ws + 5325056);      // 8,192
    int*   csrc  = (int*)(ws + 5333248);      // 8,192
    float* Wre   = ws + 5341440;              // 65,536
    float* wihre = ws + 5406976;              // 512
    float* bre   = ws + 5407488;              // 512
    unsigned* bar = (unsigned*)(ws + 5408000);

    k_bar_init<<<1, 64, 0, stream>>>(bar);
    k_persist<<<NBLK, NTHR, 0, stream>>>(enc, yprev, eps, gum, aW1, ab1, aW2, ab2,
                                         Wih, Whh, bih, bhh, fcW, fcb, fdW, fdb,
                                         feW, feb, varW, varb, pdW, pdb,
                                         encp, h2A, c2A, h2B, c2B, ctx, ytg, vsp,
                                         proj, qv, hsrc, csrc, Wre, wihre, bre,
                                         bar, out);
}

// Round 6
// 3764.397 us; speedup vs baseline: 3.1141x; 3.1141x over previous
//
#include <hip/hip_runtime.h>

#define KP 32   // particles
#define BN 256  // batch
#define TN 32   // time steps
#define ROWS (KP*BN) // 8192
#define NTHR 512

// ---------------- pre-kernel: encp, Wre/wihre/bre reorg, flag zero ----------------
// grid 8192 x 128. Stream-ordered before k_persist (no device barrier needed).
__global__ void k_pre(const float* __restrict__ enc, const float* __restrict__ W1,
                      const float* __restrict__ Whh, const float* __restrict__ Wih,
                      const float* __restrict__ bih, const float* __restrict__ bhh,
                      float* __restrict__ encp, float* __restrict__ Wre,
                      float* __restrict__ wihre, float* __restrict__ bre,
                      unsigned* __restrict__ flags) {
    int bt = blockIdx.x;           // [0, B*T)
    int e  = threadIdx.x;          // 128
    __shared__ float row[128];
    row[e] = enc[bt * 128 + e];
    __syncthreads();
    float acc = 0.f;
#pragma unroll 8
    for (int c = 0; c < 128; ++c)
        acc = fmaf(row[c], W1[(256 + c) * 128 + e], acc);
    encp[bt * 128 + e] = acc;

    if (bt < 128) {                // Wre transpose: 16384 float4
        int i = bt * 128 + e;
        int dd = i >> 7, d0 = i & 127;
        float4 v;
        v.x = Whh[dd * 512 + 0 * 128 + d0];
        v.y = Whh[dd * 512 + 1 * 128 + d0];
        v.z = Whh[dd * 512 + 2 * 128 + d0];
        v.w = Whh[dd * 512 + 3 * 128 + d0];
        ((float4*)Wre)[i] = v;
        if (i < 128) {
            float4 a;
            a.x = Wih[0 * 128 + d0]; a.y = Wih[1 * 128 + d0];
            a.z = Wih[2 * 128 + d0]; a.w = Wih[3 * 128 + d0];
            ((float4*)wihre)[d0] = a;
            float4 bb;
            bb.x = bih[0 * 128 + d0] + bhh[0 * 128 + d0];
            bb.y = bih[1 * 128 + d0] + bhh[1 * 128 + d0];
            bb.z = bih[2 * 128 + d0] + bhh[2 * 128 + d0];
            bb.w = bih[3 * 128 + d0] + bhh[3 * 128 + d0];
            ((float4*)bre)[d0] = bb;
        }
    } else if (bt < 192) {         // zero 8192 flag slots (256 x 32-uint stride)
        flags[(bt - 128) * 128 + e] = 0u;
    }
}

struct SharedS {
    float h[KP * 128], c[KP * 128], h2[KP * 128], c2[KP * 128];  // 64 KB
    float hb[128], cb[128], hcp[128], red[128];
    float aa[32], beta[32];
    float vsp[128], ctx[128];
    float proj[32], qv[32];
    float pp[32][2], qq[32][2];
    int ord[32], hjo[32], cjo[32];
    float lw[32];
    float yts;
};

// ---------------- persistent per-batch block: whole T loop, state in LDS ----------------
__global__ __launch_bounds__(NTHR, 2)
void k_persist(const float* __restrict__ enc, const float* __restrict__ yprev,
               const float* __restrict__ eps, const float* __restrict__ gum,
               const float* __restrict__ W1, const float* __restrict__ b1,
               const float* __restrict__ W2, const float* __restrict__ b2v,
               const float* __restrict__ fcW, const float* __restrict__ fcb,
               const float* __restrict__ fdW, const float* __restrict__ fdb,
               const float* __restrict__ feW, const float* __restrict__ feb,
               const float* __restrict__ varW, const float* __restrict__ varb,
               const float* __restrict__ pdW, const float* __restrict__ pdb,
               const float* __restrict__ encp, const float* __restrict__ Wre,
               const float* __restrict__ wihre, const float* __restrict__ bre,
               float* __restrict__ esg, unsigned* __restrict__ flags,
               float* __restrict__ out) {
    __shared__ SharedS sh;
    const int tid = threadIdx.x;
    const int b   = blockIdx.x;      // batch
    const int m   = b >> 5;          // norm chunk

    // zero h/c state (LDS)
#pragma unroll
    for (int i = 0; i < 2; ++i) {
        ((float4*)sh.h)[tid + NTHR * i] = make_float4(0.f, 0.f, 0.f, 0.f);
        ((float4*)sh.c)[tid + NTHR * i] = make_float4(0.f, 0.f, 0.f, 0.f);
    }
    __syncthreads();

    for (int t = 0; t < TN; ++t) {
        // ======== attn phase (tid<256 gated; identical op order to round-3) ========
        {
            if (tid < 128) {
                float s = 0.f;
#pragma unroll 4
                for (int k = 0; k < KP; ++k) s += sh.h[k * 128 + tid];
                sh.hb[tid] = s * (1.f / 32.f);
            } else if (tid < 256) {
                int d = tid - 128;
                float s = 0.f;
#pragma unroll 4
                for (int k = 0; k < KP; ++k) s += sh.c[k * 128 + d];
                sh.cb[d] = s * (1.f / 32.f);
            }
            __syncthreads();

            // phase 2: hc_proj
            float acc2 = 0.f;
            {
                int e = tid & 127, half = (tid >> 7) & 1;
                if (tid < 256) {
                    const float* Wb  = W1 + half * 128 * 128;
                    const float* hcl = half ? sh.cb : sh.hb;
#pragma unroll 8
                    for (int d = 0; d < 128; ++d)
                        acc2 = fmaf(hcl[d], Wb[d * 128 + e], acc2);
                    if (half) sh.red[e] = acc2;
                }
            }
            __syncthreads();
            if (tid < 128) sh.hcp[tid] = acc2 + sh.red[tid] + b1[tid];
            __syncthreads();

            // phase 3: scores
            if (tid < 256) {
                int w = tid >> 6, lane = tid & 63;
                for (int tt = 0; tt < 8; ++tt) {
                    int tq = w * 8 + tt;
                    float v = 0.f;
#pragma unroll
                    for (int hh = 0; hh < 2; ++hh) {
                        int e = lane + 64 * hh;
                        v += tanhf(sh.hcp[e] + encp[(b * TN + tq) * 128 + e]) * W2[e];
                    }
#pragma unroll
                    for (int off = 32; off; off >>= 1) v += __shfl_xor(v, off, 64);
                    if (lane == 0) sh.aa[tq] = v + b2v[0];
                }
            }
            __syncthreads();

            // softmax over T
            if (tid < 32) {
                float mx = -1e30f;
                for (int i = 0; i < 32; ++i) mx = fmaxf(mx, sh.aa[i]);
                float s = 0.f;
                for (int i = 0; i < 32; ++i) s += expf(sh.aa[i] - mx);
                sh.beta[tid] = expf(sh.aa[tid] - mx) / s;
            }
            __syncthreads();

            // context + y_tilde
            if (tid < 128) {
                float acc = 0.f;
#pragma unroll 4
                for (int tq = 0; tq < 32; ++tq)
                    acc = fmaf(sh.beta[tq], enc[(b * TN + tq) * 128 + tid], acc);
                sh.ctx[tid] = acc;
                sh.red[tid] = acc * fcW[tid];
            }
            __syncthreads();
            if (tid < 64) sh.red[tid] += sh.red[tid + 64];
            __syncthreads();
            if (tid < 64) {
                float v = sh.red[tid];
#pragma unroll
                for (int off = 32; off; off >>= 1) v += __shfl_xor(v, off, 64);
                if (tid == 0)
                    sh.yts = v + yprev[b * TN + t] * fcW[128] + fcb[0];
            }
            __syncthreads();

            // var + softplus
            if (tid < 128) {
                int j = tid;
                float v = fmaf(sh.yts, varW[j], varb[j]);
#pragma unroll 8
                for (int d = 0; d < 128; ++d)
                    v = fmaf(sh.hb[d], varW[(1 + d) * 128 + j], v);
                sh.vsp[j] = fmaxf(v, 0.f) + log1pf(expf(-fabsf(v)));
            }
        }
        __syncthreads();

        // ======== lstm phase: 8 waves; rows = 32 particles of batch b ========
        {
            int w = tid >> 6, c0 = tid & 63;
            int wr = w & 3, dh = w >> 2;
            int d0 = dh * 64 + c0;

            float4 wih4 = ((const float4*)wihre)[d0];
            float4 b4   = ((const float4*)bre)[d0];
            const float* wihp = (const float*)&wih4;
            const float* bp   = (const float*)&b4;
            float ytv = sh.yts;
            float acc[8][4];
#pragma unroll
            for (int r = 0; r < 8; ++r)
#pragma unroll
                for (int g = 0; g < 4; ++g)
                    acc[r][g] = fmaf(ytv, wihp[g], bp[g]);

            const float4* wp   = (const float4*)Wre + d0;
            const float*  hrow = sh.h + (wr * 8) * 128;
#pragma unroll 2
            for (int dq = 0; dq < 32; ++dq) {
                float4 wv[4];
#pragma unroll
                for (int j = 0; j < 4; ++j) wv[j] = wp[(dq * 4 + j) * 128];
                float4 hv[8];
#pragma unroll
                for (int r = 0; r < 8; ++r)
                    hv[r] = *(const float4*)&hrow[r * 128 + dq * 4];
#pragma unroll
                for (int j = 0; j < 4; ++j) {
#pragma unroll
                    for (int r = 0; r < 8; ++r) {
                        float hvj = ((const float*)&hv[r])[j];
#pragma unroll
                        for (int g = 0; g < 4; ++g)
                            acc[r][g] = fmaf(hvj, ((const float*)&wv[j])[g], acc[r][g]);
                    }
                }
            }

            float fdv = fdW[d0], pdv = pdW[d0];
#pragma unroll
            for (int r = 0; r < 8; ++r) {
                int lr = wr * 8 + r;                       // particle index
                float gi = acc[r][0], gf = acc[r][1], gg = acc[r][2], go = acc[r][3];
                float si = 1.f / (1.f + expf(-gi));
                float sf = 1.f / (1.f + expf(-gf));
                float so = 1.f / (1.f + expf(-go));
                float tg = tanhf(gg);
                float cold = sh.c[lr * 128 + d0];
                float cnv = sf * cold + si * tg;
                float hnv = so * tanhf(cnv);
                hnv = fmaf(eps[((size_t)t * ROWS + lr * BN + b) * 128 + d0],
                           sh.vsp[d0], hnv);
                sh.c2[lr * 128 + d0] = cnv;
                sh.h2[lr * 128 + d0] = hnv;
                float p = hnv * fdv, q = hnv * pdv;
#pragma unroll
                for (int off = 32; off; off >>= 1) {
                    p += __shfl_xor(p, off, 64);
                    q += __shfl_xor(q, off, 64);
                }
                if (c0 == 0) { sh.pp[lr][dh] = p; sh.qq[lr][dh] = q; }
            }
            __syncthreads();
            if (tid < 32) sh.proj[tid] = sh.pp[tid][0] + sh.pp[tid][1];
            else if (tid < 64) sh.qv[tid - 32] = sh.qq[tid - 32][0] + sh.qq[tid - 32][1];
        }
        __syncthreads();

        // ======== resample: sort, pdf, chunk-exchange, gumbel-max, gather ========
        float esj = 0.f;
        if (tid < 32) {
            int j = tid;
            float pj = sh.proj[j];
            int r = 0;
#pragma unroll 8
            for (int l = 0; l < 32; ++l) {
                float pl = sh.proj[l];
                r += (pl < pj) || (pl == pj && l < j);
            }
            sh.ord[r] = j;
        }
        __syncthreads();
        if (tid < 32) {
            int j = tid;
            int jo = sh.ord[j];
            float lp = sh.qv[jo] + sh.yts * pdW[128] + pdb[0];
            esj = expf(lp);
            esg[(size_t)(t & 1) * (BN * KP) + b * KP + j] = esj;
        }
        __threadfence();
        __syncthreads();
        if (tid == 0)
            __hip_atomic_store(&flags[b * 32], (unsigned)(t + 1),
                               __ATOMIC_RELEASE, __HIP_MEMORY_SCOPE_AGENT);
        // poll chunk-mates' flags (32 distinct cachelines, parallel)
        if (tid < 32) {
            while (__hip_atomic_load(&flags[(m * 32 + tid) * 32],
                                     __ATOMIC_ACQUIRE, __HIP_MEMORY_SCOPE_AGENT)
                   < (unsigned)(t + 1))
                __builtin_amdgcn_s_sleep(2);
        }
        __syncthreads();
        __threadfence();
        if (tid < 32) {
            int j = tid;
            const float* eb = esg + (size_t)(t & 1) * (BN * KP) + (m * 32) * KP + j;
            float S = 0.f;
#pragma unroll 8
            for (int l = 0; l < 32; ++l) S += eb[l * KP];   // l ascending (view(-1,K) bug)
            sh.lw[j] = logf(esj / S + 1e-30f);
        }
        __syncthreads();
        if (tid < 32) {
            int j = tid;
            const float* gb = gum + (((size_t)t * BN + b) * KP + j) * KP;
            float best = -1e38f;
            int bi = 0;
#pragma unroll 8
            for (int l = 0; l < 32; ++l) {
                float v = sh.lw[l] + gb[l];
                if (v > best) { best = v; bi = l; }
            }
            sh.hjo[j] = sh.ord[bi];   // sorted h2 -> original index
            sh.cjo[j] = bi;           // unsorted c2 with sorted-space idx (ref bug)
        }
        __syncthreads();
        // physical gather in LDS
#pragma unroll
        for (int it = 0; it < 2; ++it) {
            int i = tid + NTHR * it;       // 1024 float4 per array
            int r = i >> 5, o = i & 31;
            ((float4*)sh.h)[i] = ((float4*)sh.h2)[sh.hjo[r] * 32 + o];
            ((float4*)sh.c)[i] = ((float4*)sh.c2)[sh.cjo[r] * 32 + o];
        }
        __syncthreads();
    }

    // ======== final: out[b] ========
    if (tid < 64) {
        int lane = tid;
        float acc = 0.f;
#pragma unroll
        for (int hh = 0; hh < 2; ++hh) {
            int d = lane + 64 * hh;
            float s = 0.f;
#pragma unroll 4
            for (int k = 0; k < KP; ++k) s += sh.h[k * 128 + d];
            acc = fmaf(s * (1.f / 32.f), fdW[d], acc);
            acc = fmaf(sh.ctx[d], feW[d], acc);
        }
#pragma unroll
        for (int off = 32; off; off >>= 1) acc += __shfl_xor(acc, off, 64);
        if (lane == 0) out[b] = acc + fdb[0] + feb[0];
    }
}

extern "C" void kernel_launch(void* const* d_in, const int* in_sizes, int n_in,
                              void* d_out, int out_size, void* d_ws, size_t ws_size,
                              hipStream_t stream) {
    const float* enc   = (const float*)d_in[0];
    const float* yprev = (const float*)d_in[1];
    const float* eps   = (const float*)d_in[2];
    const float* gum   = (const float*)d_in[3];
    const float* aW1   = (const float*)d_in[4];
    const float* ab1   = (const float*)d_in[5];
    const float* aW2   = (const float*)d_in[6];
    const float* ab2   = (const float*)d_in[7];
    const float* Wih   = (const float*)d_in[8];
    const float* Whh   = (const float*)d_in[9];
    const float* bih   = (const float*)d_in[10];
    const float* bhh   = (const float*)d_in[11];
    const float* fcW   = (const float*)d_in[12];
    const float* fcb   = (const float*)d_in[13];
    const float* fdW   = (const float*)d_in[14];
    const float* fdb   = (const float*)d_in[15];
    const float* feW   = (const float*)d_in[16];
    const float* feb   = (const float*)d_in[17];
    const float* varW  = (const float*)d_in[18];
    const float* varb  = (const float*)d_in[19];
    const float* pdW   = (const float*)d_in[20];
    const float* pdb   = (const float*)d_in[21];
    float* out = (float*)d_out;

    float* ws     = (float*)d_ws;
    float* encp   = ws;                         // 1,048,576 floats
    float* Wre    = ws + 1048576;               // 65,536
    float* wihre  = ws + 1114112;               // 512
    float* bre    = ws + 1114624;               // 512
    float* esg    = ws + 1115136;               // 16,384 (2 x 256 x 32)
    unsigned* flags = (unsigned*)(ws + 1131520);// 8,192 uints (256 x 32 stride)

    k_pre<<<BN * TN, 128, 0, stream>>>(enc, aW1, Whh, Wih, bih, bhh,
                                       encp, Wre, wihre, bre, flags);
    k_persist<<<BN, NTHR, 0, stream>>>(enc, yprev, eps, gum, aW1, ab1, aW2, ab2,
                                       fcW, fcb, fdW, fdb, feW, feb, varW, varb,
                                       pdW, pdb, encp, Wre, wihre, bre,
                                       esg, flags, out);
}

// Round 8
// 1671.731 us; speedup vs baseline: 7.0124x; 2.2518x over previous
//
#include <hip/hip_runtime.h>

#define KP 32   // particles
#define BN 256  // batch
#define TN 32   // time steps
#define ROWS (KP*BN) // 8192
#define NTHR 512

// ---------------- pre-kernel: encp, Wre/wihre/bre reorg, flag zero ----------------
// grid 8192 x 128. Stream-ordered before k_persist (no device barrier needed).
__global__ void k_pre(const float* __restrict__ enc, const float* __restrict__ W1,
                      const float* __restrict__ Whh, const float* __restrict__ Wih,
                      const float* __restrict__ bih, const float* __restrict__ bhh,
                      float* __restrict__ encp, float* __restrict__ Wre,
                      float* __restrict__ wihre, float* __restrict__ bre,
                      unsigned* __restrict__ flags) {
    int bt = blockIdx.x;           // [0, B*T)
    int e  = threadIdx.x;          // 128
    __shared__ float row[128];
    row[e] = enc[bt * 128 + e];
    __syncthreads();
    float acc = 0.f;
#pragma unroll 8
    for (int c = 0; c < 128; ++c)
        acc = fmaf(row[c], W1[(256 + c) * 128 + e], acc);
    encp[bt * 128 + e] = acc;

    if (bt < 128) {                // Wre transpose: 16384 float4
        int i = bt * 128 + e;
        int dd = i >> 7, d0 = i & 127;
        float4 v;
        v.x = Whh[dd * 512 + 0 * 128 + d0];
        v.y = Whh[dd * 512 + 1 * 128 + d0];
        v.z = Whh[dd * 512 + 2 * 128 + d0];
        v.w = Whh[dd * 512 + 3 * 128 + d0];
        ((float4*)Wre)[i] = v;
        if (i < 128) {
            float4 a;
            a.x = Wih[0 * 128 + d0]; a.y = Wih[1 * 128 + d0];
            a.z = Wih[2 * 128 + d0]; a.w = Wih[3 * 128 + d0];
            ((float4*)wihre)[d0] = a;
            float4 bb;
            bb.x = bih[0 * 128 + d0] + bhh[0 * 128 + d0];
            bb.y = bih[1 * 128 + d0] + bhh[1 * 128 + d0];
            bb.z = bih[2 * 128 + d0] + bhh[2 * 128 + d0];
            bb.w = bih[3 * 128 + d0] + bhh[3 * 128 + d0];
            ((float4*)bre)[d0] = bb;
        }
    } else if (bt < 192) {         // zero 8192 flag slots (256 x 32-uint stride)
        flags[(bt - 128) * 128 + e] = 0u;
    }
}

struct SharedS {
    float h[KP * 128], c[KP * 128], h2[KP * 128], c2[KP * 128];  // 64 KB
    float hb[128], cb[128], hcp[128], red[128];
    float aa[32], beta[32];
    float vsp[128], ctx[128];
    float proj[32], qv[32];
    float pp[32][2], qq[32][2];
    int ord[32], hjo[32], cjo[32];
    float lw[32];
    float yts;
};

// ---------------- persistent per-batch block: whole T loop, state in LDS ----------------
__global__ __launch_bounds__(NTHR, 2)
void k_persist(const float* __restrict__ enc, const float* __restrict__ yprev,
               const float* __restrict__ eps, const float* __restrict__ gum,
               const float* __restrict__ W1, const float* __restrict__ b1,
               const float* __restrict__ W2, const float* __restrict__ b2v,
               const float* __restrict__ fcW, const float* __restrict__ fcb,
               const float* __restrict__ fdW, const float* __restrict__ fdb,
               const float* __restrict__ feW, const float* __restrict__ feb,
               const float* __restrict__ varW, const float* __restrict__ varb,
               const float* __restrict__ pdW, const float* __restrict__ pdb,
               const float* __restrict__ encp, const float* __restrict__ Wre,
               const float* __restrict__ wihre, const float* __restrict__ bre,
               float* __restrict__ esg, unsigned* __restrict__ flags,
               float* __restrict__ out) {
    __shared__ SharedS sh;
    const int tid = threadIdx.x;
    const int b   = blockIdx.x;      // batch
    const int m   = b >> 5;          // norm chunk

    const int w_  = tid >> 6, c0_ = tid & 63;
    const int wr_ = w_ & 3, dh_ = w_ >> 2;
    const int d0_ = dh_ * 64 + c0_;

    // zero h/c state (LDS)
#pragma unroll
    for (int i = 0; i < 2; ++i) {
        ((float4*)sh.h)[tid + NTHR * i] = make_float4(0.f, 0.f, 0.f, 0.f);
        ((float4*)sh.c)[tid + NTHR * i] = make_float4(0.f, 0.f, 0.f, 0.f);
    }
    __syncthreads();

    for (int t = 0; t < TN; ++t) {
        // ---- prefetch this step's eps into registers (pure input; latency hides under attn) ----
        float epr[8];
        {
            const float* ep = eps + (size_t)t * ROWS * 128
                            + (size_t)(wr_ * 8) * BN * 128 + (size_t)b * 128 + d0_;
#pragma unroll
            for (int r = 0; r < 8; ++r)
                epr[r] = ep[(size_t)r * BN * 128];
        }

        // ======== attn phase (tid<256 gated; identical op order to round-3) ========
        {
            if (tid < 128) {
                float s = 0.f;
#pragma unroll 4
                for (int k = 0; k < KP; ++k) s += sh.h[k * 128 + tid];
                sh.hb[tid] = s * (1.f / 32.f);
            } else if (tid < 256) {
                int d = tid - 128;
                float s = 0.f;
#pragma unroll 4
                for (int k = 0; k < KP; ++k) s += sh.c[k * 128 + d];
                sh.cb[d] = s * (1.f / 32.f);
            }
            __syncthreads();

            // phase 2: hc_proj
            float acc2 = 0.f;
            {
                int e = tid & 127, half = (tid >> 7) & 1;
                if (tid < 256) {
                    const float* Wb  = W1 + half * 128 * 128;
                    const float* hcl = half ? sh.cb : sh.hb;
#pragma unroll 8
                    for (int d = 0; d < 128; ++d)
                        acc2 = fmaf(hcl[d], Wb[d * 128 + e], acc2);
                    if (half) sh.red[e] = acc2;
                }
            }
            __syncthreads();
            if (tid < 128) sh.hcp[tid] = acc2 + sh.red[tid] + b1[tid];
            __syncthreads();

            // phase 3: scores
            if (tid < 256) {
                int w = tid >> 6, lane = tid & 63;
                for (int tt = 0; tt < 8; ++tt) {
                    int tq = w * 8 + tt;
                    float v = 0.f;
#pragma unroll
                    for (int hh = 0; hh < 2; ++hh) {
                        int e = lane + 64 * hh;
                        v += tanhf(sh.hcp[e] + encp[(b * TN + tq) * 128 + e]) * W2[e];
                    }
#pragma unroll
                    for (int off = 32; off; off >>= 1) v += __shfl_xor(v, off, 64);
                    if (lane == 0) sh.aa[tq] = v + b2v[0];
                }
            }
            __syncthreads();

            // softmax over T
            if (tid < 32) {
                float mx = -1e30f;
                for (int i = 0; i < 32; ++i) mx = fmaxf(mx, sh.aa[i]);
                float s = 0.f;
                for (int i = 0; i < 32; ++i) s += expf(sh.aa[i] - mx);
                sh.beta[tid] = expf(sh.aa[tid] - mx) / s;
            }
            __syncthreads();

            // context + y_tilde
            if (tid < 128) {
                float acc = 0.f;
#pragma unroll 4
                for (int tq = 0; tq < 32; ++tq)
                    acc = fmaf(sh.beta[tq], enc[(b * TN + tq) * 128 + tid], acc);
                sh.ctx[tid] = acc;
                sh.red[tid] = acc * fcW[tid];
            }
            __syncthreads();
            if (tid < 64) sh.red[tid] += sh.red[tid + 64];
            __syncthreads();
            if (tid < 64) {
                float v = sh.red[tid];
#pragma unroll
                for (int off = 32; off; off >>= 1) v += __shfl_xor(v, off, 64);
                if (tid == 0)
                    sh.yts = v + yprev[b * TN + t] * fcW[128] + fcb[0];
            }
            __syncthreads();

            // var + softplus
            if (tid < 128) {
                int j = tid;
                float v = fmaf(sh.yts, varW[j], varb[j]);
#pragma unroll 8
                for (int d = 0; d < 128; ++d)
                    v = fmaf(sh.hb[d], varW[(1 + d) * 128 + j], v);
                sh.vsp[j] = fmaxf(v, 0.f) + log1pf(expf(-fabsf(v)));
            }
        }
        __syncthreads();

        // ======== lstm phase: 8 waves; rows = 32 particles of batch b ========
        {
            float4 wih4 = ((const float4*)wihre)[d0_];
            float4 b4   = ((const float4*)bre)[d0_];
            const float* wihp = (const float*)&wih4;
            const float* bp   = (const float*)&b4;
            float ytv = sh.yts;
            float acc[8][4];
#pragma unroll
            for (int r = 0; r < 8; ++r)
#pragma unroll
                for (int g = 0; g < 4; ++g)
                    acc[r][g] = fmaf(ytv, wihp[g], bp[g]);

            const float4* wp   = (const float4*)Wre + d0_;
            const float*  hrow = sh.h + (wr_ * 8) * 128;
#pragma unroll 2
            for (int dq = 0; dq < 32; ++dq) {
                float4 wv[4];
#pragma unroll
                for (int j = 0; j < 4; ++j) wv[j] = wp[(dq * 4 + j) * 128];
                float4 hv[8];
#pragma unroll
                for (int r = 0; r < 8; ++r)
                    hv[r] = *(const float4*)&hrow[r * 128 + dq * 4];
#pragma unroll
                for (int j = 0; j < 4; ++j) {
#pragma unroll
                    for (int r = 0; r < 8; ++r) {
                        float hvj = ((const float*)&hv[r])[j];
#pragma unroll
                        for (int g = 0; g < 4; ++g)
                            acc[r][g] = fmaf(hvj, ((const float*)&wv[j])[g], acc[r][g]);
                    }
                }
            }

            float fdv = fdW[d0_], pdv = pdW[d0_];
#pragma unroll
            for (int r = 0; r < 8; ++r) {
                int lr = wr_ * 8 + r;                      // particle index
                float gi = acc[r][0], gf = acc[r][1], gg = acc[r][2], go = acc[r][3];
                float si = 1.f / (1.f + expf(-gi));
                float sf = 1.f / (1.f + expf(-gf));
                float so = 1.f / (1.f + expf(-go));
                float tg = tanhf(gg);
                float cold = sh.c[lr * 128 + d0_];
                float cnv = sf * cold + si * tg;
                float hnv = so * tanhf(cnv);
                hnv = fmaf(epr[r], sh.vsp[d0_], hnv);
                sh.c2[lr * 128 + d0_] = cnv;
                sh.h2[lr * 128 + d0_] = hnv;
                float p = hnv * fdv, q = hnv * pdv;
#pragma unroll
                for (int off = 32; off; off >>= 1) {
                    p += __shfl_xor(p, off, 64);
                    q += __shfl_xor(q, off, 64);
                }
                if (c0_ == 0) { sh.pp[lr][dh_] = p; sh.qq[lr][dh_] = q; }
            }
            __syncthreads();
            if (tid < 32) sh.proj[tid] = sh.pp[tid][0] + sh.pp[tid][1];
            else if (tid < 64) sh.qv[tid - 32] = sh.qq[tid - 32][0] + sh.qq[tid - 32][1];
        }
        __syncthreads();

        // ======== resample: sort, pdf, INV-FREE chunk-exchange, gumbel-max, gather ========
        if (tid < 32) {
            int j = tid;
            float pj = sh.proj[j];
            int r = 0;
#pragma unroll 8
            for (int l = 0; l < 32; ++l) {
                float pl = sh.proj[l];
                r += (pl < pj) || (pl == pj && l < j);
            }
            sh.ord[r] = j;
        }
        __syncthreads();
        float esj = 0.f;
        if (tid < 32) {
            int j = tid;
            int jo = sh.ord[j];
            float lp = sh.qv[jo] + sh.yts * pdW[128] + pdb[0];
            esj = expf(lp);
            esg[(size_t)(t & 1) * (BN * KP) + b * KP + j] = esj;
            // release: push esg to the coherence point BEFORE flag store (wb, no inv)
            __builtin_amdgcn_fence(__ATOMIC_RELEASE, "agent");
            if (j == 0)
                __hip_atomic_store(&flags[b * 32], (unsigned)(t + 1),
                                   __ATOMIC_RELAXED, __HIP_MEMORY_SCOPE_AGENT);
            // relaxed spin: agent-scope atomic loads bypass stale L2, NO invalidation
            while (__hip_atomic_load(&flags[(m * 32 + j) * 32],
                                     __ATOMIC_RELAXED, __HIP_MEMORY_SCOPE_AGENT)
                   < (unsigned)(t + 1))
                __builtin_amdgcn_s_sleep(2);
        }
        __syncthreads();
        asm volatile("" ::: "memory");
        if (tid < 32) {
            int j = tid;
            const float* eb = esg + (size_t)(t & 1) * (BN * KP) + (m * 32) * KP + j;
            float S = 0.f;
#pragma unroll 8
            for (int l = 0; l < 32; ++l)   // l ascending (view(-1,K) bug); IC-fresh atomic reads
                S += __hip_atomic_load(&eb[l * KP], __ATOMIC_RELAXED, __HIP_MEMORY_SCOPE_AGENT);
            sh.lw[j] = logf(esj / S + 1e-30f);
        }
        __syncthreads();
        if (tid < 32) {
            int j = tid;
            const float* gb = gum + (((size_t)t * BN + b) * KP + j) * KP;
            float best = -1e38f;
            int bi = 0;
#pragma unroll 8
            for (int l = 0; l < 32; ++l) {
                float v = sh.lw[l] + gb[l];
                if (v > best) { best = v; bi = l; }
            }
            sh.hjo[j] = sh.ord[bi];   // sorted h2 -> original index
            sh.cjo[j] = bi;           // unsorted c2 with sorted-space idx (ref bug)
        }
        __syncthreads();
        // physical gather in LDS
#pragma unroll
        for (int it = 0; it < 2; ++it) {
            int i = tid + NTHR * it;       // 1024 float4 per array
            int r = i >> 5, o = i & 31;
            ((float4*)sh.h)[i] = ((float4*)sh.h2)[sh.hjo[r] * 32 + o];
            ((float4*)sh.c)[i] = ((float4*)sh.c2)[sh.cjo[r] * 32 + o];
        }
        __syncthreads();
    }

    // ======== final: out[b] ========
    if (tid < 64) {
        int lane = tid;
        float acc = 0.f;
#pragma unroll
        for (int hh = 0; hh < 2; ++hh) {
            int d = lane + 64 * hh;
            float s = 0.f;
#pragma unroll 4
            for (int k = 0; k < KP; ++k) s += sh.h[k * 128 + d];
            acc = fmaf(s * (1.f / 32.f), fdW[d], acc);
            acc = fmaf(sh.ctx[d], feW[d], acc);
        }
#pragma unroll
        for (int off = 32; off; off >>= 1) acc += __shfl_xor(acc, off, 64);
        if (lane == 0) out[b] = acc + fdb[0] + feb[0];
    }
}

extern "C" void kernel_launch(void* const* d_in, const int* in_sizes, int n_in,
                              void* d_out, int out_size, void* d_ws, size_t ws_size,
                              hipStream_t stream) {
    const float* enc   = (const float*)d_in[0];
    const float* yprev = (const float*)d_in[1];
    const float* eps   = (const float*)d_in[2];
    const float* gum   = (const float*)d_in[3];
    const float* aW1   = (const float*)d_in[4];
    const float* ab1   = (const float*)d_in[5];
    const float* aW2   = (const float*)d_in[6];
    const float* ab2   = (const float*)d_in[7];
    const float* Wih   = (const float*)d_in[8];
    const float* Whh   = (const float*)d_in[9];
    const float* bih   = (const float*)d_in[10];
    const float* bhh   = (const float*)d_in[11];
    const float* fcW   = (const float*)d_in[12];
    const float* fcb   = (const float*)d_in[13];
    const float* fdW   = (const float*)d_in[14];
    const float* fdb   = (const float*)d_in[15];
    const float* feW   = (const float*)d_in[16];
    const float* feb   = (const float*)d_in[17];
    const float* varW  = (const float*)d_in[18];
    const float* varb  = (const float*)d_in[19];
    const float* pdW   = (const float*)d_in[20];
    const float* pdb   = (const float*)d_in[21];
    float* out = (float*)d_out;

    float* ws     = (float*)d_ws;
    float* encp   = ws;                         // 1,048,576 floats
    float* Wre    = ws + 1048576;               // 65,536
    float* wihre  = ws + 1114112;               // 512
    float* bre    = ws + 1114624;               // 512
    float* esg    = ws + 1115136;               // 16,384 (2 x 256 x 32)
    unsigned* flags = (unsigned*)(ws + 1131520);// 8,192 uints (256 x 32 stride)

    k_pre<<<BN * TN, 128, 0, stream>>>(enc, aW1, Whh, Wih, bih, bhh,
                                       encp, Wre, wihre, bre, flags);
    k_persist<<<BN, NTHR, 0, stream>>>(enc, yprev, eps, gum, aW1, ab1, aW2, ab2,
                                       fcW, fcb, fdW, fdb, feW, feb, varW, varb,
                                       pdW, pdb, encp, Wre, wihre, bre,
                                       esg, flags, out);
}

// Round 10
// 1507.304 us; speedup vs baseline: 7.7773x; 1.1091x over previous
//
#include <hip/hip_runtime.h>

#define KP 32   // particles
#define BN 256  // batch
#define TN 32   // time steps
#define ROWS (KP*BN) // 8192
#define NTHR 1024

// ---------------- pre-kernel: encp, Wre/wihre/bre reorg, flag zero ----------------
__global__ void k_pre(const float* __restrict__ enc, const float* __restrict__ W1,
                      const float* __restrict__ Whh, const float* __restrict__ Wih,
                      const float* __restrict__ bih, const float* __restrict__ bhh,
                      float* __restrict__ encp, float* __restrict__ Wre,
                      float* __restrict__ wihre, float* __restrict__ bre,
                      unsigned* __restrict__ flags) {
    int bt = blockIdx.x;           // [0, B*T)
    int e  = threadIdx.x;          // 128
    __shared__ float row[128];
    row[e] = enc[bt * 128 + e];
    __syncthreads();
    float acc = 0.f;
#pragma unroll 8
    for (int c = 0; c < 128; ++c)
        acc = fmaf(row[c], W1[(256 + c) * 128 + e], acc);
    encp[bt * 128 + e] = acc;

    if (bt < 128) {                // Wre transpose: 16384 float4
        int i = bt * 128 + e;
        int dd = i >> 7, d0 = i & 127;
        float4 v;
        v.x = Whh[dd * 512 + 0 * 128 + d0];
        v.y = Whh[dd * 512 + 1 * 128 + d0];
        v.z = Whh[dd * 512 + 2 * 128 + d0];
        v.w = Whh[dd * 512 + 3 * 128 + d0];
        ((float4*)Wre)[i] = v;
        if (i < 128) {
            float4 a;
            a.x = Wih[0 * 128 + d0]; a.y = Wih[1 * 128 + d0];
            a.z = Wih[2 * 128 + d0]; a.w = Wih[3 * 128 + d0];
            ((float4*)wihre)[d0] = a;
            float4 bb;
            bb.x = bih[0 * 128 + d0] + bhh[0 * 128 + d0];
            bb.y = bih[1 * 128 + d0] + bhh[1 * 128 + d0];
            bb.z = bih[2 * 128 + d0] + bhh[2 * 128 + d0];
            bb.w = bih[3 * 128 + d0] + bhh[3 * 128 + d0];
            ((float4*)bre)[d0] = bb;
        }
    } else if (bt < 192) {         // zero 8192 flag slots (256 x 32-uint stride)
        flags[(bt - 128) * 128 + e] = 0u;
    }
}

struct SharedS {
    float h[KP * 128], c[KP * 128], h2[KP * 128], c2[KP * 128];  // 64 KB
    float hb[128], cb[128], hcp[128], red[128];
    float aa[32], beta[32];
    float vsp[128], ctx[128];
    float proj[32], qv[32];
    float pp[32][2], qq[32][2];
    int ord[32], hjo[32], cjo[32];
    float lw[32];
    float yts;
};

// ---------------- persistent per-batch block: whole T loop, state in LDS ----------------
// 1024 thr = 16 waves: wave w -> particles (w&7)*4..+4, d0-half (w>>3). VGPR<=128 -> 16 waves/CU.
__global__ __launch_bounds__(NTHR, 4)
void k_persist(const float* __restrict__ enc, const float* __restrict__ yprev,
               const float* __restrict__ eps, const float* __restrict__ gum,
               const float* __restrict__ W1, const float* __restrict__ b1,
               const float* __restrict__ W2, const float* __restrict__ b2v,
               const float* __restrict__ fcW, const float* __restrict__ fcb,
               const float* __restrict__ fdW, const float* __restrict__ fdb,
               const float* __restrict__ feW, const float* __restrict__ feb,
               const float* __restrict__ varW, const float* __restrict__ varb,
               const float* __restrict__ pdW, const float* __restrict__ pdb,
               const float* __restrict__ encp, const float* __restrict__ Wre,
               const float* __restrict__ wihre, const float* __restrict__ bre,
               float* __restrict__ esg, unsigned* __restrict__ flags,
               float* __restrict__ out) {
    __shared__ SharedS sh;
    const int tid = threadIdx.x;
    const int b   = blockIdx.x;      // batch
    const int m   = b >> 5;          // norm chunk

    const int w_  = tid >> 6, c0_ = tid & 63;
    const int pg_ = w_ & 7, dh_ = w_ >> 3;
    const int d0_ = dh_ * 64 + c0_;

    // zero h/c state (LDS): exactly 1024 float4 per array
    ((float4*)sh.h)[tid] = make_float4(0.f, 0.f, 0.f, 0.f);
    ((float4*)sh.c)[tid] = make_float4(0.f, 0.f, 0.f, 0.f);
    __syncthreads();

    for (int t = 0; t < TN; ++t) {
        // ---- prefetch this step's eps into registers (latency hides under attn) ----
        float epr[4];
        {
            const float* ep = eps + (size_t)t * ROWS * 128
                            + (size_t)(pg_ * 4) * BN * 128 + (size_t)b * 128 + d0_;
#pragma unroll
            for (int r = 0; r < 4; ++r)
                epr[r] = ep[(size_t)r * BN * 128];
        }

        // ======== attn phase (gated; op order identical to round-3) ========
        {
            if (tid < 128) {
                float s = 0.f;
#pragma unroll 4
                for (int k = 0; k < KP; ++k) s += sh.h[k * 128 + tid];
                sh.hb[tid] = s * (1.f / 32.f);
            } else if (tid < 256) {
                int d = tid - 128;
                float s = 0.f;
#pragma unroll 4
                for (int k = 0; k < KP; ++k) s += sh.c[k * 128 + d];
                sh.cb[d] = s * (1.f / 32.f);
            }
            __syncthreads();

            // phase 2: hc_proj
            float acc2 = 0.f;
            {
                int e = tid & 127, half = (tid >> 7) & 1;
                if (tid < 256) {
                    const float* Wb  = W1 + half * 128 * 128;
                    const float* hcl = half ? sh.cb : sh.hb;
#pragma unroll 8
                    for (int d = 0; d < 128; ++d)
                        acc2 = fmaf(hcl[d], Wb[d * 128 + e], acc2);
                    if (half) sh.red[e] = acc2;
                }
            }
            __syncthreads();
            if (tid < 128) sh.hcp[tid] = acc2 + sh.red[tid] + b1[tid];
            __syncthreads();

            // phase 3: scores — all 16 waves, 2 tq each (per-tq math unchanged)
            {
                int lane = tid & 63;
#pragma unroll
                for (int tt = 0; tt < 2; ++tt) {
                    int tq = w_ * 2 + tt;
                    float v = 0.f;
#pragma unroll
                    for (int hh = 0; hh < 2; ++hh) {
                        int e = lane + 64 * hh;
                        v += tanhf(sh.hcp[e] + encp[(b * TN + tq) * 128 + e]) * W2[e];
                    }
#pragma unroll
                    for (int off = 32; off; off >>= 1) v += __shfl_xor(v, off, 64);
                    if (lane == 0) sh.aa[tq] = v + b2v[0];
                }
            }
            __syncthreads();

            // softmax over T
            if (tid < 32) {
                float mx = -1e30f;
                for (int i = 0; i < 32; ++i) mx = fmaxf(mx, sh.aa[i]);
                float s = 0.f;
                for (int i = 0; i < 32; ++i) s += expf(sh.aa[i] - mx);
                sh.beta[tid] = expf(sh.aa[tid] - mx) / s;
            }
            __syncthreads();

            // context + y_tilde
            if (tid < 128) {
                float acc = 0.f;
#pragma unroll 4
                for (int tq = 0; tq < 32; ++tq)
                    acc = fmaf(sh.beta[tq], enc[(b * TN + tq) * 128 + tid], acc);
                sh.ctx[tid] = acc;
                sh.red[tid] = acc * fcW[tid];
            }
            __syncthreads();
            if (tid < 64) {          // fused two-stage reduce (same adds, one sync saved)
                float v = sh.red[tid] + sh.red[tid + 64];
#pragma unroll
                for (int off = 32; off; off >>= 1) v += __shfl_xor(v, off, 64);
                if (tid == 0)
                    sh.yts = v + yprev[b * TN + t] * fcW[128] + fcb[0];
            }
            __syncthreads();

            // var + softplus
            if (tid < 128) {
                int j = tid;
                float v = fmaf(sh.yts, varW[j], varb[j]);
#pragma unroll 8
                for (int d = 0; d < 128; ++d)
                    v = fmaf(sh.hb[d], varW[(1 + d) * 128 + j], v);
                sh.vsp[j] = fmaxf(v, 0.f) + log1pf(expf(-fabsf(v)));
            }
        }
        __syncthreads();

        // ======== lstm phase: 16 waves; wave = 4 particles x 64 d0 ========
        {
            float4 wih4 = ((const float4*)wihre)[d0_];
            float4 b4   = ((const float4*)bre)[d0_];
            const float* wihp = (const float*)&wih4;
            const float* bp   = (const float*)&b4;
            float ytv = sh.yts;
            float acc[4][4];
#pragma unroll
            for (int r = 0; r < 4; ++r)
#pragma unroll
                for (int g = 0; g < 4; ++g)
                    acc[r][g] = fmaf(ytv, wihp[g], bp[g]);

            const float4* wp   = (const float4*)Wre + d0_;
            const float*  hrow = sh.h + (pg_ * 4) * 128;
#pragma unroll 2
            for (int dq = 0; dq < 32; ++dq) {
                float4 wv[4];
#pragma unroll
                for (int j = 0; j < 4; ++j) wv[j] = wp[(dq * 4 + j) * 128];
                float4 hv[4];
#pragma unroll
                for (int r = 0; r < 4; ++r)
                    hv[r] = *(const float4*)&hrow[r * 128 + dq * 4];
#pragma unroll
                for (int j = 0; j < 4; ++j) {
#pragma unroll
                    for (int r = 0; r < 4; ++r) {
                        float hvj = ((const float*)&hv[r])[j];
#pragma unroll
                        for (int g = 0; g < 4; ++g)
                            acc[r][g] = fmaf(hvj, ((const float*)&wv[j])[g], acc[r][g]);
                    }
                }
            }

            float fdv = fdW[d0_], pdv = pdW[d0_];
#pragma unroll
            for (int r = 0; r < 4; ++r) {
                int lr = pg_ * 4 + r;                      // particle index
                float gi = acc[r][0], gf = acc[r][1], gg = acc[r][2], go = acc[r][3];
                float si = 1.f / (1.f + expf(-gi));
                float sf = 1.f / (1.f + expf(-gf));
                float so = 1.f / (1.f + expf(-go));
                float tg = tanhf(gg);
                float cold = sh.c[lr * 128 + d0_];
                float cnv = sf * cold + si * tg;
                float hnv = so * tanhf(cnv);
                hnv = fmaf(epr[r], sh.vsp[d0_], hnv);
                sh.c2[lr * 128 + d0_] = cnv;
                sh.h2[lr * 128 + d0_] = hnv;
                float p = hnv * fdv, q = hnv * pdv;
#pragma unroll
                for (int off = 32; off; off >>= 1) {
                    p += __shfl_xor(p, off, 64);
                    q += __shfl_xor(q, off, 64);
                }
                if (c0_ == 0) { sh.pp[lr][dh_] = p; sh.qq[lr][dh_] = q; }
            }
            __syncthreads();
            if (tid < 32) sh.proj[tid] = sh.pp[tid][0] + sh.pp[tid][1];
            else if (tid < 64) sh.qv[tid - 32] = sh.qq[tid - 32][0] + sh.qq[tid - 32][1];
        }
        __syncthreads();

        // ======== resample: sort+pdf+publish+poll (wave-0 local, no internal syncs) ========
        float esj = 0.f;
        if (tid < 32) {
            int j = tid;
            float pj = sh.proj[j];
            int r = 0;
#pragma unroll 8
            for (int l = 0; l < 32; ++l) {
                float pl = sh.proj[l];
                r += (pl < pj) || (pl == pj && l < j);
            }
            sh.ord[r] = j;
            // intra-wave LDS handoff: no __syncthreads needed (same wave, program order)
            int jo = sh.ord[j];
            float lp = sh.qv[jo] + sh.yts * pdW[128] + pdb[0];
            esj = expf(lp);
            esg[(size_t)(t & 1) * (BN * KP) + b * KP + j] = esj;
            // release: push esg to the coherence point BEFORE flag store (wb, no inv)
            __builtin_amdgcn_fence(__ATOMIC_RELEASE, "agent");
            if (j == 0)
                __hip_atomic_store(&flags[b * 32], (unsigned)(t + 1),
                                   __ATOMIC_RELAXED, __HIP_MEMORY_SCOPE_AGENT);
            // relaxed spin: agent-scope atomic loads bypass stale L2, NO invalidation
            while (__hip_atomic_load(&flags[(m * 32 + j) * 32],
                                     __ATOMIC_RELAXED, __HIP_MEMORY_SCOPE_AGENT)
                   < (unsigned)(t + 1))
                __builtin_amdgcn_s_sleep(2);
            asm volatile("" ::: "memory");
            const float* eb = esg + (size_t)(t & 1) * (BN * KP) + (m * 32) * KP + j;
            float S = 0.f;
#pragma unroll 8
            for (int l = 0; l < 32; ++l)   // l ascending (view(-1,K) bug); IC-fresh atomic reads
                S += __hip_atomic_load(&eb[l * KP], __ATOMIC_RELAXED, __HIP_MEMORY_SCOPE_AGENT);
            sh.lw[j] = logf(esj / S + 1e-30f);
            // gumbel-max (lw written by same wave)
            const float* gb = gum + (((size_t)t * BN + b) * KP + j) * KP;
            float best = -1e38f;
            int bi = 0;
#pragma unroll 8
            for (int l = 0; l < 32; ++l) {
                float v = sh.lw[l] + gb[l];
                if (v > best) { best = v; bi = l; }
            }
            sh.hjo[j] = sh.ord[bi];   // sorted h2 -> original index
            sh.cjo[j] = bi;           // unsorted c2 with sorted-space idx (ref bug)
        }
        __syncthreads();
        // physical gather in LDS: exactly 1024 float4 per array (tid covers all)
        {
            int r = tid >> 5, o = tid & 31;
            ((float4*)sh.h)[tid] = ((float4*)sh.h2)[sh.hjo[r] * 32 + o];
            ((float4*)sh.c)[tid] = ((float4*)sh.c2)[sh.cjo[r] * 32 + o];
        }
        __syncthreads();
    }

    // ======== final: out[b] ========
    if (tid < 64) {
        int lane = tid;
        float acc = 0.f;
#pragma unroll
        for (int hh = 0; hh < 2; ++hh) {
            int d = lane + 64 * hh;
            float s = 0.f;
#pragma unroll 4
            for (int k = 0; k < KP; ++k) s += sh.h[k * 128 + d];
            acc = fmaf(s * (1.f / 32.f), fdW[d], acc);
            acc = fmaf(sh.ctx[d], feW[d], acc);
        }
#pragma unroll
        for (int off = 32; off; off >>= 1) acc += __shfl_xor(acc, off, 64);
        if (lane == 0) out[b] = acc + fdb[0] + feb[0];
    }
}

extern "C" void kernel_launch(void* const* d_in, const int* in_sizes, int n_in,
                              void* d_out, int out_size, void* d_ws, size_t ws_size,
                              hipStream_t stream) {
    const float* enc   = (const float*)d_in[0];
    const float* yprev = (const float*)d_in[1];
    const float* eps   = (const float*)d_in[2];
    const float* gum   = (const float*)d_in[3];
    const float* aW1   = (const float*)d_in[4];
    const float* ab1   = (const float*)d_in[5];
    const float* aW2   = (const float*)d_in[6];
    const float* ab2   = (const float*)d_in[7];
    const float* Wih   = (const float*)d_in[8];
    const float* Whh   = (const float*)d_in[9];
    const float* bih   = (const float*)d_in[10];
    const float* bhh   = (const float*)d_in[11];
    const float* fcW   = (const float*)d_in[12];
    const float* fcb   = (const float*)d_in[13];
    const float* fdW   = (const float*)d_in[14];
    const float* fdb   = (const float*)d_in[15];
    const float* feW   = (const float*)d_in[16];
    const float* feb   = (const float*)d_in[17];
    const float* varW  = (const float*)d_in[18];
    const float* varb  = (const float*)d_in[19];
    const float* pdW   = (const float*)d_in[20];
    const float* pdb   = (const float*)d_in[21];
    float* out = (float*)d_out;

    float* ws     = (float*)d_ws;
    float* encp   = ws;                         // 1,048,576 floats
    float* Wre    = ws + 1048576;               // 65,536
    float* wihre  = ws + 1114112;               // 512
    float* bre    = ws + 1114624;               // 512
    float* esg    = ws + 1115136;               // 16,384 (2 x 256 x 32)
    unsigned* flags = (unsigned*)(ws + 1131520);// 8,192 uints (256 x 32 stride)

    k_pre<<<BN * TN, 128, 0, stream>>>(enc, aW1, Whh, Wih, bih, bhh,
                                       encp, Wre, wihre, bre, flags);
    k_persist<<<BN, NTHR, 0, stream>>>(enc, yprev, eps, gum, aW1, ab1, aW2, ab2,
                                       fcW, fcb, fdW, fdb, feW, feb, varW, varb,
                                       pdW, pdb, encp, Wre, wihre, bre,
                                       esg, flags, out);
}